// Round 4
// baseline (219.636 us; speedup 1.0000x reference)
//
#include <hip/hip_runtime.h>

// Problem constants
#define S_LEN   2048
#define N_HEAD  16
#define WINSZ   256
#define ATT_SCALE 0.125f   // 1/sqrt(64)

typedef short bf16x8 __attribute__((ext_vector_type(8)));   // 8 bf16 (4 VGPRs) MFMA A/B frag
typedef float f32x4  __attribute__((ext_vector_type(4)));   // MFMA C/D frag

__device__ __forceinline__ unsigned short f2bf(float f) {   // RNE
    union { float f; unsigned u; } x; x.f = f;
    return (unsigned short)((x.u + 0x7FFFu + ((x.u >> 16) & 1u)) >> 16);
}
__device__ __forceinline__ unsigned short f2bf_rhu(float f) {  // round-half-up (cheap)
    union { float f; unsigned u; } x; x.f = f;
    return (unsigned short)((x.u + 0x8000u) >> 16);
}

// async global -> LDS, 16 B per lane (global_load_lds_dwordx4). LDS dest is
// wave-uniform base + lane*16 (m104/m108); the global address may be per-lane.
__device__ __forceinline__ void gl2lds16(const unsigned short* g, unsigned short* l) {
    __builtin_amdgcn_global_load_lds(
        (const __attribute__((address_space(1))) unsigned int*)g,
        (__attribute__((address_space(3))) unsigned int*)l, 16, 0, 0);
}

// ---------------- fused fp32 -> bf16 conversion (all three tensors) ----------------
__global__ void cvt_all(const float* __restrict__ x, const float* __restrict__ wqkv,
                        const float* __restrict__ wout,
                        unsigned short* __restrict__ xb, unsigned short* __restrict__ wqkvb,
                        unsigned short* __restrict__ woutb) {
    int i = blockIdx.x * 256 + threadIdx.x;   // float4 units; total 2097152
    const float4* src; ushort4* dst; int off;
    if (i < 1048576)              { src = (const float4*)x;    dst = (ushort4*)xb;    off = i; }
    else if (i < 1048576 + 786432){ src = (const float4*)wqkv; dst = (ushort4*)wqkvb; off = i - 1048576; }
    else                          { src = (const float4*)wout; dst = (ushort4*)woutb; off = i - 1835008; }
    float4 v = src[off];
    ushort4 o;
    o.x = f2bf(v.x); o.y = f2bf(v.y); o.z = f2bf(v.z); o.w = f2bf(v.w);
    dst[off] = o;
}

// ---------------- bf16 GEMM: C[M,N] = A[M,K] * B[N,K]^T ----------------
// BK=64, global_load_lds width-16 staging with XOR-swizzled 16B chunks.
// Epilogue stages C through LDS for fully-coalesced 16B stores.
// MODE 0 (BN=128): qkv scatter. q,k blocks (bn<16) write [b,h,s,64]; v blocks
//   (bn>=16) compute C^T in-loop (swapped MFMA operands) and write Vt [b,h,64,s].
// MODE 1 (BN=64): fp32 C + bias.
template<int MODE, int BN>
__global__ __launch_bounds__(256, 3)
void gemm_bt(const unsigned short* __restrict__ A, const unsigned short* __restrict__ Bm,
             int K,
             unsigned short* __restrict__ qout, unsigned short* __restrict__ kout,
             unsigned short* __restrict__ vtout,
             float* __restrict__ Cout, const float* __restrict__ bias, int N)
{
    constexpr int NJ = BN / 32;                 // n-frags per wave (4 or 2)
    __shared__ __align__(16) unsigned char smem[34816];   // staging (<=32KB) / epilogue tile
    unsigned short* Als = (unsigned short*)smem;          // 128 x 64
    unsigned short* Bls = Als + 128 * 64;                 // BN x 64

    const int tid   = threadIdx.x;
    const int lane  = tid & 63;
    const int wave  = tid >> 6;
    const int bm    = blockIdx.y, bn = blockIdx.x;
    const int wm    = (wave >> 1) * 64;
    const int wn    = (wave & 1) * (BN / 2);
    const int col16 = lane & 15;
    const int quad  = lane >> 4;
    const bool transc = (MODE == 0) && (bn >= 16);   // block-uniform

    f32x4 acc[4][NJ];
#pragma unroll
    for (int i = 0; i < 4; ++i)
#pragma unroll
        for (int j = 0; j < NJ; ++j)
            acc[i][j] = f32x4{0.f, 0.f, 0.f, 0.f};

    // staging: each gl2lds16 fills 8 rows x 64ch. lane l -> row (l>>3),
    // GLOBAL 16B-chunk ((l&7)^(l>>3)) stored at PHYS chunk (l&7):
    // phys chunk p of LDS row r holds logical chunk p ^ (r&7).
    const int    grow     = lane >> 3;
    const int    gchk     = (lane & 7) ^ grow;
    const size_t laneoff  = (size_t)grow * K + gchk * 8;
    const unsigned short* gA = A  + (size_t)(bm * 128) * K + laneoff;
    const unsigned short* gB = Bm + (size_t)(bn * BN)  * K + laneoff;

    for (int k0 = 0; k0 < K; k0 += 64) {
        __syncthreads();
#pragma unroll
        for (int i = 0; i < 4; ++i) {
            const int r0 = wave * 32 + i * 8;
            gl2lds16(gA + (size_t)r0 * K + k0, &Als[r0 * 64]);
        }
#pragma unroll
        for (int i = 0; i < BN / 32; ++i) {
            const int r0 = wave * (BN / 4) + i * 8;
            gl2lds16(gB + (size_t)r0 * K + k0, &Bls[r0 * 64]);
        }
        __syncthreads();

#pragma unroll
        for (int kc = 0; kc < 2; ++kc) {
            bf16x8 af[4], bfr[NJ];
            const int sw = (kc * 4 + quad) ^ (col16 & 7);   // de-swizzle
#pragma unroll
            for (int i = 0; i < 4; ++i)
                af[i]  = *(const bf16x8*)(&Als[(wm + i * 16 + col16) * 64 + sw * 8]);
#pragma unroll
            for (int j = 0; j < NJ; ++j)
                bfr[j] = *(const bf16x8*)(&Bls[(wn + j * 16 + col16) * 64 + sw * 8]);
            if (transc) {
#pragma unroll
                for (int i = 0; i < 4; ++i)
#pragma unroll
                    for (int j = 0; j < NJ; ++j)
                        acc[i][j] = __builtin_amdgcn_mfma_f32_16x16x32_bf16(bfr[j], af[i], acc[i][j], 0, 0, 0);
            } else {
#pragma unroll
                for (int i = 0; i < 4; ++i)
#pragma unroll
                    for (int j = 0; j < NJ; ++j)
                        acc[i][j] = __builtin_amdgcn_mfma_f32_16x16x32_bf16(af[i], bfr[j], acc[i][j], 0, 0, 0);
            }
        }
    }

    // ---------- epilogue via LDS (C row = quad*4+reg, col = lane&15) ----------
    __syncthreads();   // all frag reads done; safe to overwrite staging
    if (MODE == 0) {
        unsigned short* Ct = (unsigned short*)smem;   // 128 x 136
        if (!transc) {
#pragma unroll
            for (int i = 0; i < 4; ++i)
#pragma unroll
                for (int j = 0; j < NJ; ++j)
#pragma unroll
                    for (int r = 0; r < 4; ++r)
                        Ct[(wm + i * 16 + quad * 4 + r) * 136 + wn + j * 16 + col16] =
                            f2bf(acc[i][j][r]);
        } else {  // acc holds C^T: rows = n_local, cols = m_local
#pragma unroll
            for (int i = 0; i < 4; ++i)
#pragma unroll
                for (int j = 0; j < NJ; ++j)
#pragma unroll
                    for (int r = 0; r < 4; ++r)
                        Ct[(wn + j * 16 + quad * 4 + r) * 136 + wm + i * 16 + col16] =
                            f2bf(acc[i][j][r]);
        }
        __syncthreads();
        const int row  = tid >> 1;      // 0..127
        const int half = tid & 1;
        const unsigned short* src = &Ct[row * 136 + half * 64];
        if (bn < 16) {                  // q or k: row = s-row, cols = 2 heads x 64d
            int m = bm * 128 + row;
            int b = m >> 11, s = m & 2047;
            int h = (bn & 7) * 2 + half;
            unsigned short* dst = (bn < 8 ? qout : kout) +
                                  (((size_t)(b * 16 + h) * 2048 + s) * 64);
#pragma unroll
            for (int c = 0; c < 8; ++c)
                *(bf16x8*)(dst + c * 8) = *(const bf16x8*)(src + c * 8);
        } else {                        // v: row = n_local (head-d), cols = s
            int h = ((bn - 16) * 128 + row) >> 6;
            int d = row & 63;
            int b = bm >> 4;
            int s0 = (bm & 15) * 128 + half * 64;
            unsigned short* dst = vtout + ((size_t)(b * 16 + h) * 64 + d) * 2048 + s0;
#pragma unroll
            for (int c = 0; c < 8; ++c)
                *(bf16x8*)(dst + c * 8) = *(const bf16x8*)(src + c * 8);
        }
    } else {
        float* Cf = (float*)smem;       // 128 x 68
#pragma unroll
        for (int i = 0; i < 4; ++i)
#pragma unroll
            for (int j = 0; j < NJ; ++j)
#pragma unroll
                for (int r = 0; r < 4; ++r)
                    Cf[(wm + i * 16 + quad * 4 + r) * 68 + wn + j * 16 + col16] = acc[i][j][r];
        __syncthreads();
        const int row  = tid >> 1;
        const int half = tid & 1;
        int m = bm * 128 + row;
#pragma unroll
        for (int c = 0; c < 8; ++c) {
            int nl = half * 32 + c * 4;
            float4 v  = *(const float4*)&Cf[row * 68 + nl];
            float4 bb = *(const float4*)&bias[bn * 64 + nl];
            v.x += bb.x; v.y += bb.y; v.z += bb.z; v.w += bb.w;
            *(float4*)&Cout[(size_t)m * N + bn * 64 + nl] = v;
        }
    }
}

// ---------------- banded flash attention ----------------
// 128-query blocks, 8 waves x 16 queries (512 threads -> 16 waves/CU at 2 blocks).
// 64-key chunks staged via global_load_lds with XOR-chunk swizzle. Fixed-max
// softmax: p = exp(s*scale - 8) (scores bounded); exp(-8) cancels in O = PV/l.
__global__ __launch_bounds__(512, 4)
void attn_kernel(const unsigned short* __restrict__ Qg, const unsigned short* __restrict__ Kg,
                 const unsigned short* __restrict__ Vtg, unsigned short* __restrict__ ctx)
{
    __shared__ unsigned short Kls[64 * 64];        // 8 KB   [key][ch], swizzled chunks
    __shared__ unsigned short Vls[64 * 64];        // 8 KB   [d][key],  swizzled chunks
    __shared__ unsigned short Pls[8][16 * 72];     // 18 KB  per-wave P (LP=72)

    const int tid  = threadIdx.x;
    const int lane = tid & 63;
    const int wave = tid >> 6;            // 0..7
    const int col  = lane & 15;
    const int quad = lane >> 4;

    const int bh  = blockIdx.y;           // b*16 + h
    const int Q0  = blockIdx.x * 128;
    const int q0w = Q0 + wave * 16;

    const unsigned short* Qb  = Qg  + (size_t)bh * S_LEN * 64;
    const unsigned short* Kb  = Kg  + (size_t)bh * S_LEN * 64;
    const unsigned short* Vtb = Vtg + (size_t)bh * 64 * S_LEN;

    // Q fragment (A-operand m=lane&15, k=quad*8+j), two 32-channel chunks
    bf16x8 qa[2];
#pragma unroll
    for (int kc = 0; kc < 2; ++kc)
        qa[kc] = *(const bf16x8*)(Qb + (size_t)(q0w + col) * 64 + kc * 32 + quad * 8);

    f32x4 acc[4];
    float lsum[4];
#pragma unroll
    for (int d = 0; d < 4; ++d) acc[d] = f32x4{0.f, 0.f, 0.f, 0.f};
#pragma unroll
    for (int r = 0; r < 4; ++r) lsum[r] = 0.f;

    // staging lane roles (per wave: one 8-row K call + one 8-row V call)
    const int rsub = lane >> 3;                 // 0..7
    const int gch  = (lane & 7) ^ rsub;         // swizzled logical chunk
    const int swz  = quad;                      // de-swizzle helper below uses kc

    for (int c = 0; c < 10; ++c) {           // 10*64 = 640 keys covers [Q0-256, Q0+383]
        const int kb = Q0 - WINSZ + c * 64;
        __syncthreads();                     // previous-iter readers done
        {
            int krow = kb + wave * 8 + rsub;
            krow = krow < 0 ? 0 : (krow > S_LEN - 1 ? S_LEN - 1 : krow);
            gl2lds16(Kb + (size_t)krow * 64 + gch * 8, &Kls[wave * 512]);
            int drow = wave * 8 + rsub;
            int ss = kb + gch * 8;           // 8-granular; OOB keys masked below
            ss = ss < 0 ? 0 : (ss > S_LEN - 8 ? S_LEN - 8 : ss);
            gl2lds16(Vtb + (size_t)drow * S_LEN + ss, &Vls[wave * 512]);
        }
        __syncthreads();                     // drains vmcnt before barrier

        // wave-uniform skip of fully-masked chunks (both barriers already done)
        if (kb > q0w + 15 + WINSZ || kb + 63 < q0w - WINSZ || kb > S_LEN - 1 || kb + 63 < 0)
            continue;

        // S = Q K^T : 4 key-groups of 16
        f32x4 sc[4];
#pragma unroll
        for (int hf = 0; hf < 4; ++hf) {
            const int rw = (hf * 16 + col) * 64;
            const int s0 = ((0 * 4 + swz) ^ (col & 7)) * 8;
            const int s1 = ((1 * 4 + swz) ^ (col & 7)) * 8;
            bf16x8 kf0 = *(const bf16x8*)(&Kls[rw + s0]);
            bf16x8 kf1 = *(const bf16x8*)(&Kls[rw + s1]);
            f32x4 z = f32x4{0.f, 0.f, 0.f, 0.f};
            z = __builtin_amdgcn_mfma_f32_16x16x32_bf16(qa[0], kf0, z, 0, 0, 0);
            sc[hf] = __builtin_amdgcn_mfma_f32_16x16x32_bf16(qa[1], kf1, z, 0, 0, 0);
        }

        const bool full = (kb >= q0w + 15 - WINSZ) && (kb + 63 <= q0w + WINSZ) &&
                          (kb >= 0) && (kb + 63 <= S_LEN - 1);

        // p = exp(s*scale - 8); mask only boundary chunks
        float p[4][4];
#pragma unroll
        for (int hf = 0; hf < 4; ++hf) {
            const int kkey = kb + hf * 16 + col;
#pragma unroll
            for (int r = 0; r < 4; ++r) {
                float e = __expf(fmaf(sc[hf][r], ATT_SCALE, -8.0f));
                if (!full) {
                    int q  = q0w + quad * 4 + r;
                    int dq = kkey - q;
                    bool valid = (kkey >= 0) && (kkey < S_LEN) && (dq <= WINSZ) && (dq >= -WINSZ);
                    e = valid ? e : 0.f;
                }
                p[hf][r] = e;
                lsum[r] += e;
            }
        }

        // P (C-layout) -> wave-private LDS -> A-layout frags
        unsigned short* pw = &Pls[wave][0];
#pragma unroll
        for (int hf = 0; hf < 4; ++hf)
#pragma unroll
            for (int r = 0; r < 4; ++r)
                pw[(quad * 4 + r) * 72 + hf * 16 + col] = f2bf_rhu(p[hf][r]);
        asm volatile("s_waitcnt lgkmcnt(0)" ::: "memory");
        bf16x8 pf[2];
        pf[0] = *(const bf16x8*)(&pw[col * 72 + quad * 8]);
        pf[1] = *(const bf16x8*)(&pw[col * 72 + 32 + quad * 8]);

        // O += P V : B-frags from transposed-V rows (swizzled chunks)
#pragma unroll
        for (int d = 0; d < 4; ++d) {
            const int rw = (d * 16 + col) * 64;
#pragma unroll
            for (int kc = 0; kc < 2; ++kc) {
                const int so = ((kc * 4 + swz) ^ (col & 7)) * 8;
                bf16x8 vf = *(const bf16x8*)(&Vls[rw + so]);
                acc[d] = __builtin_amdgcn_mfma_f32_16x16x32_bf16(pf[kc], vf, acc[d], 0, 0, 0);
            }
        }
    }

    // epilogue: final l-reduction, normalize, write ctx bf16 [b, s, h*64+d]
    const int b = bh >> 4, h = bh & 15;
#pragma unroll
    for (int r = 0; r < 4; ++r) {
        float v = lsum[r];
        v += __shfl_xor(v, 1);
        v += __shfl_xor(v, 2);
        v += __shfl_xor(v, 4);
        v += __shfl_xor(v, 8);
        float inv = 1.f / v;
        int q = q0w + quad * 4 + r;
#pragma unroll
        for (int d = 0; d < 4; ++d)
            ctx[((size_t)(b * S_LEN + q)) * 1024 + h * 64 + d * 16 + col] =
                f2bf(acc[d][r] * inv);
    }
}

// ---------------- launch ----------------
extern "C" void kernel_launch(void* const* d_in, const int* in_sizes, int n_in,
                              void* d_out, int out_size, void* d_ws, size_t ws_size,
                              hipStream_t stream) {
    const float* x    = (const float*)d_in[0];   // [2,2048,1024]
    const float* Wqkv = (const float*)d_in[1];   // [3072,1024]
    const float* Wout = (const float*)d_in[2];   // [1024,1024]
    const float* bout = (const float*)d_in[3];   // [1024]
    float* out = (float*)d_out;                  // [2,2048,1024] fp32

    char* ws = (char*)d_ws;
    unsigned short* xb    = (unsigned short*)(ws);                        // 4096x1024 bf16 (8 MB)
    unsigned short* wqkvb = (unsigned short*)(ws + 8u  * 1024 * 1024);    // 3072x1024 (6 MB)
    unsigned short* woutb = (unsigned short*)(ws + 14u * 1024 * 1024);    // 1024x1024 (2 MB)
    unsigned short* qb    = (unsigned short*)(ws + 16u * 1024 * 1024);    // [2,16,2048,64] (8 MB)
    unsigned short* kbuf  = (unsigned short*)(ws + 24u * 1024 * 1024);    // [2,16,2048,64] (8 MB)
    unsigned short* vtbuf = (unsigned short*)(ws + 32u * 1024 * 1024);    // [2,16,64,2048] (8 MB)
    unsigned short* ctxb  = (unsigned short*)(ws + 40u * 1024 * 1024);    // 4096x1024 (8 MB)

    cvt_all<<<8192, 256, 0, stream>>>(x, Wqkv, Wout, xb, wqkvb, woutb);

    // qkv = x @ Wqkv^T  -> q/k row-major, V transposed (C^T computed in-loop)
    gemm_bt<0, 128><<<dim3(24, 32), 256, 0, stream>>>(xb, wqkvb, 1024, qb, kbuf, vtbuf,
                                                      nullptr, nullptr, 0);
    // banded attention -> ctx  (16 q-tiles x 32 batch*heads, 512 threads)
    attn_kernel<<<dim3(16, 32), 512, 0, stream>>>(qb, kbuf, vtbuf, ctxb);
    // out = ctx @ Wout^T + b_out
    gemm_bt<1, 64><<<dim3(16, 32), 256, 0, stream>>>(ctxb, woutb, 1024, nullptr, nullptr, nullptr,
                                                     out, bout, 1024);
}

// Round 5
// 212.348 us; speedup vs baseline: 1.0343x; 1.0343x over previous
//
#include <hip/hip_runtime.h>

// Problem constants
#define S_LEN   2048
#define N_HEAD  16
#define WINSZ   256
#define ATT_SCALE 0.125f   // 1/sqrt(64)

typedef short bf16x8 __attribute__((ext_vector_type(8)));   // 8 bf16 (4 VGPRs) MFMA A/B frag
typedef float f32x4  __attribute__((ext_vector_type(4)));   // MFMA C/D frag

__device__ __forceinline__ unsigned short f2bf(float f) {   // RNE
    union { float f; unsigned u; } x; x.f = f;
    return (unsigned short)((x.u + 0x7FFFu + ((x.u >> 16) & 1u)) >> 16);
}
__device__ __forceinline__ unsigned short f2bf_rhu(float f) {  // round-half-up (cheap)
    union { float f; unsigned u; } x; x.f = f;
    return (unsigned short)((x.u + 0x8000u) >> 16);
}

// async global -> LDS, 16 B per lane (global_load_lds_dwordx4). LDS dest is
// wave-uniform base + lane*16 (m104/m108); the global address may be per-lane.
__device__ __forceinline__ void gl2lds16(const unsigned short* g, unsigned short* l) {
    __builtin_amdgcn_global_load_lds(
        (const __attribute__((address_space(1))) unsigned int*)g,
        (__attribute__((address_space(3))) unsigned int*)l, 16, 0, 0);
}

// ---------------- fused fp32 -> bf16 conversion (all three tensors) ----------------
__global__ void cvt_all(const float* __restrict__ x, const float* __restrict__ wqkv,
                        const float* __restrict__ wout,
                        unsigned short* __restrict__ xb, unsigned short* __restrict__ wqkvb,
                        unsigned short* __restrict__ woutb) {
    int i = blockIdx.x * 256 + threadIdx.x;   // float4 units; total 2097152
    const float4* src; ushort4* dst; int off;
    if (i < 1048576)              { src = (const float4*)x;    dst = (ushort4*)xb;    off = i; }
    else if (i < 1048576 + 786432){ src = (const float4*)wqkv; dst = (ushort4*)wqkvb; off = i - 1048576; }
    else                          { src = (const float4*)wout; dst = (ushort4*)woutb; off = i - 1835008; }
    float4 v = src[off];
    ushort4 o;
    o.x = f2bf(v.x); o.y = f2bf(v.y); o.z = f2bf(v.z); o.w = f2bf(v.w);
    dst[off] = o;
}

// ---------------- bf16 GEMM: C[M,N] = A[M,K] * B[N,K]^T ----------------
// BK=64, global_load_lds width-16 staging with XOR-swizzled 16B chunks.
// Epilogue stages C through LDS; store mapping is WAVE-CONTIGUOUS: per store
// instruction, 8 lanes cover one 128-B contiguous global run (full sectors).
// MODE 0 (BN=128): qkv scatter. q,k blocks (bn<16) write [b,h,s,64]; v blocks
//   (bn>=16) compute C^T in-loop (swapped MFMA operands) and write Vt [b,h,64,s].
// MODE 1 (BN=64): fp32 C + bias.
template<int MODE, int BN>
__global__ __launch_bounds__(256, 3)
void gemm_bt(const unsigned short* __restrict__ A, const unsigned short* __restrict__ Bm,
             int K,
             unsigned short* __restrict__ qout, unsigned short* __restrict__ kout,
             unsigned short* __restrict__ vtout,
             float* __restrict__ Cout, const float* __restrict__ bias, int N)
{
    constexpr int NJ = BN / 32;                 // n-frags per wave (4 or 2)
    __shared__ __align__(16) unsigned char smem[34816];   // staging / epilogue tile
    unsigned short* Als = (unsigned short*)smem;          // 128 x 64
    unsigned short* Bls = Als + 128 * 64;                 // BN x 64

    const int tid   = threadIdx.x;
    const int lane  = tid & 63;
    const int wave  = tid >> 6;
    const int bm    = blockIdx.y, bn = blockIdx.x;
    const int wm    = (wave >> 1) * 64;
    const int wn    = (wave & 1) * (BN / 2);
    const int col16 = lane & 15;
    const int quad  = lane >> 4;
    const bool transc = (MODE == 0) && (bn >= 16);   // block-uniform

    f32x4 acc[4][NJ];
#pragma unroll
    for (int i = 0; i < 4; ++i)
#pragma unroll
        for (int j = 0; j < NJ; ++j)
            acc[i][j] = f32x4{0.f, 0.f, 0.f, 0.f};

    // staging: each gl2lds16 fills 8 rows x 64ch. lane l -> row (l>>3),
    // GLOBAL 16B-chunk ((l&7)^(l>>3)) stored at PHYS chunk (l&7):
    // phys chunk p of LDS row r holds logical chunk p ^ (r&7).
    const int    grow     = lane >> 3;
    const int    gchk     = (lane & 7) ^ grow;
    const size_t laneoff  = (size_t)grow * K + gchk * 8;
    const unsigned short* gA = A  + (size_t)(bm * 128) * K + laneoff;
    const unsigned short* gB = Bm + (size_t)(bn * BN)  * K + laneoff;

    for (int k0 = 0; k0 < K; k0 += 64) {
        __syncthreads();
#pragma unroll
        for (int i = 0; i < 4; ++i) {
            const int r0 = wave * 32 + i * 8;
            gl2lds16(gA + (size_t)r0 * K + k0, &Als[r0 * 64]);
        }
#pragma unroll
        for (int i = 0; i < BN / 32; ++i) {
            const int r0 = wave * (BN / 4) + i * 8;
            gl2lds16(gB + (size_t)r0 * K + k0, &Bls[r0 * 64]);
        }
        __syncthreads();

#pragma unroll
        for (int kc = 0; kc < 2; ++kc) {
            bf16x8 af[4], bfr[NJ];
            const int sw = (kc * 4 + quad) ^ (col16 & 7);   // de-swizzle
#pragma unroll
            for (int i = 0; i < 4; ++i)
                af[i]  = *(const bf16x8*)(&Als[(wm + i * 16 + col16) * 64 + sw * 8]);
#pragma unroll
            for (int j = 0; j < NJ; ++j)
                bfr[j] = *(const bf16x8*)(&Bls[(wn + j * 16 + col16) * 64 + sw * 8]);
            if (transc) {
#pragma unroll
                for (int i = 0; i < 4; ++i)
#pragma unroll
                    for (int j = 0; j < NJ; ++j)
                        acc[i][j] = __builtin_amdgcn_mfma_f32_16x16x32_bf16(bfr[j], af[i], acc[i][j], 0, 0, 0);
            } else {
#pragma unroll
                for (int i = 0; i < 4; ++i)
#pragma unroll
                    for (int j = 0; j < NJ; ++j)
                        acc[i][j] = __builtin_amdgcn_mfma_f32_16x16x32_bf16(af[i], bfr[j], acc[i][j], 0, 0, 0);
            }
        }
    }

    // ---------- epilogue via LDS (C row = quad*4+reg, col = lane&15) ----------
    __syncthreads();   // all frag reads done; safe to overwrite staging
    if (MODE == 0) {
        unsigned short* Ct = (unsigned short*)smem;   // 128 x 136 bf16
        if (!transc) {
#pragma unroll
            for (int i = 0; i < 4; ++i)
#pragma unroll
                for (int j = 0; j < NJ; ++j)
#pragma unroll
                    for (int r = 0; r < 4; ++r)
                        Ct[(wm + i * 16 + quad * 4 + r) * 136 + wn + j * 16 + col16] =
                            f2bf(acc[i][j][r]);
        } else {  // acc holds C^T: rows = n_local, cols = m_local
#pragma unroll
            for (int i = 0; i < 4; ++i)
#pragma unroll
                for (int j = 0; j < NJ; ++j)
#pragma unroll
                    for (int r = 0; r < 4; ++r)
                        Ct[(wn + j * 16 + quad * 4 + r) * 136 + wm + i * 16 + col16] =
                            f2bf(acc[i][j][r]);
        }
        __syncthreads();
        // wave-contiguous stores: iteration c -> 32 row-halves (8 per wave);
        // 8 lanes x 16 B = one 128-B contiguous run per row-half.
        const int lsub = lane >> 3;   // 0..7: row-half within wave
        const int chk  = lane & 7;    // 16-B chunk within the 128-B run
#pragma unroll
        for (int c = 0; c < 8; ++c) {
            const int rh   = c * 32 + wave * 8 + lsub;   // 0..255
            const int row  = rh >> 1;
            const int half = rh & 1;
            bf16x8 v = *(const bf16x8*)(&Ct[row * 136 + half * 64 + chk * 8]);
            if (bn < 16) {              // q or k: row = s-row, halves = 2 heads
                int m = bm * 128 + row;
                int b = m >> 11, s = m & 2047;
                int h = (bn & 7) * 2 + half;
                unsigned short* dst = (bn < 8 ? qout : kout) +
                                      (((size_t)(b * 16 + h) * 2048 + s) * 64) + chk * 8;
                *(bf16x8*)dst = v;
            } else {                    // v: row = n_local (head-d), halves = s-halves
                int h = ((bn - 16) * 128 + row) >> 6;
                int d = row & 63;
                int b = bm >> 4;
                int s0 = (bm & 15) * 128 + half * 64;
                unsigned short* dst = vtout + ((size_t)(b * 16 + h) * 64 + d) * 2048 + s0 + chk * 8;
                *(bf16x8*)dst = v;
            }
        }
    } else {
        float* Cf = (float*)smem;       // 128 x 68 fp32
#pragma unroll
        for (int i = 0; i < 4; ++i)
#pragma unroll
            for (int j = 0; j < NJ; ++j)
#pragma unroll
                for (int r = 0; r < 4; ++r)
                    Cf[(wm + i * 16 + quad * 4 + r) * 68 + wn + j * 16 + col16] = acc[i][j][r];
        __syncthreads();
        // wave-contiguous: row-half = 128 B (32 floats); 8 lanes per run.
        const int lsub = lane >> 3;
        const int chk  = lane & 7;
#pragma unroll
        for (int c = 0; c < 8; ++c) {
            const int rh   = c * 32 + wave * 8 + lsub;   // 0..255
            const int row  = rh >> 1;
            const int half = rh & 1;
            const int nl   = half * 32 + chk * 4;
            float4 v  = *(const float4*)&Cf[row * 68 + nl];
            float4 bb = *(const float4*)&bias[bn * 64 + nl];
            v.x += bb.x; v.y += bb.y; v.z += bb.z; v.w += bb.w;
            int m = bm * 128 + row;
            *(float4*)&Cout[(size_t)m * N + bn * 64 + nl] = v;
        }
    }
}

// ---------------- banded flash attention ----------------
// 128-query blocks, 8 waves x 16 queries (512 threads -> 16 waves/CU at 2 blocks).
// 64-key chunks staged via global_load_lds with XOR-chunk swizzle. Fixed-max
// softmax: p = exp(s*scale - 8) (scores bounded); exp(-8) cancels in O = PV/l.
__global__ __launch_bounds__(512, 4)
void attn_kernel(const unsigned short* __restrict__ Qg, const unsigned short* __restrict__ Kg,
                 const unsigned short* __restrict__ Vtg, unsigned short* __restrict__ ctx)
{
    __shared__ unsigned short Kls[64 * 64];        // 8 KB   [key][ch], swizzled chunks
    __shared__ unsigned short Vls[64 * 64];        // 8 KB   [d][key],  swizzled chunks
    __shared__ unsigned short Pls[8][16 * 72];     // 18 KB  per-wave P (LP=72)

    const int tid  = threadIdx.x;
    const int lane = tid & 63;
    const int wave = tid >> 6;            // 0..7
    const int col  = lane & 15;
    const int quad = lane >> 4;

    const int bh  = blockIdx.y;           // b*16 + h
    const int Q0  = blockIdx.x * 128;
    const int q0w = Q0 + wave * 16;

    const unsigned short* Qb  = Qg  + (size_t)bh * S_LEN * 64;
    const unsigned short* Kb  = Kg  + (size_t)bh * S_LEN * 64;
    const unsigned short* Vtb = Vtg + (size_t)bh * 64 * S_LEN;

    // Q fragment (A-operand m=lane&15, k=quad*8+j), two 32-channel chunks
    bf16x8 qa[2];
#pragma unroll
    for (int kc = 0; kc < 2; ++kc)
        qa[kc] = *(const bf16x8*)(Qb + (size_t)(q0w + col) * 64 + kc * 32 + quad * 8);

    f32x4 acc[4];
    float lsum[4];
#pragma unroll
    for (int d = 0; d < 4; ++d) acc[d] = f32x4{0.f, 0.f, 0.f, 0.f};
#pragma unroll
    for (int r = 0; r < 4; ++r) lsum[r] = 0.f;

    // staging lane roles (per wave: one 8-row K call + one 8-row V call)
    const int rsub = lane >> 3;                 // 0..7
    const int gch  = (lane & 7) ^ rsub;         // swizzled logical chunk
    const int swz  = quad;

    for (int c = 0; c < 10; ++c) {           // 10*64 = 640 keys covers [Q0-256, Q0+383]
        const int kb = Q0 - WINSZ + c * 64;
        __syncthreads();                     // previous-iter readers done
        {
            int krow = kb + wave * 8 + rsub;
            krow = krow < 0 ? 0 : (krow > S_LEN - 1 ? S_LEN - 1 : krow);
            gl2lds16(Kb + (size_t)krow * 64 + gch * 8, &Kls[wave * 512]);
            int drow = wave * 8 + rsub;
            int ss = kb + gch * 8;           // 8-granular; OOB keys masked below
            ss = ss < 0 ? 0 : (ss > S_LEN - 8 ? S_LEN - 8 : ss);
            gl2lds16(Vtb + (size_t)drow * S_LEN + ss, &Vls[wave * 512]);
        }
        __syncthreads();                     // drains vmcnt before barrier

        // wave-uniform skip of fully-masked chunks (both barriers already done)
        if (kb > q0w + 15 + WINSZ || kb + 63 < q0w - WINSZ || kb > S_LEN - 1 || kb + 63 < 0)
            continue;

        // S = Q K^T : 4 key-groups of 16
        f32x4 sc[4];
#pragma unroll
        for (int hf = 0; hf < 4; ++hf) {
            const int rw = (hf * 16 + col) * 64;
            const int s0 = ((0 * 4 + swz) ^ (col & 7)) * 8;
            const int s1 = ((1 * 4 + swz) ^ (col & 7)) * 8;
            bf16x8 kf0 = *(const bf16x8*)(&Kls[rw + s0]);
            bf16x8 kf1 = *(const bf16x8*)(&Kls[rw + s1]);
            f32x4 z = f32x4{0.f, 0.f, 0.f, 0.f};
            z = __builtin_amdgcn_mfma_f32_16x16x32_bf16(qa[0], kf0, z, 0, 0, 0);
            sc[hf] = __builtin_amdgcn_mfma_f32_16x16x32_bf16(qa[1], kf1, z, 0, 0, 0);
        }

        const bool full = (kb >= q0w + 15 - WINSZ) && (kb + 63 <= q0w + WINSZ) &&
                          (kb >= 0) && (kb + 63 <= S_LEN - 1);

        // p = exp(s*scale - 8); mask only boundary chunks
        float p[4][4];
#pragma unroll
        for (int hf = 0; hf < 4; ++hf) {
            const int kkey = kb + hf * 16 + col;
#pragma unroll
            for (int r = 0; r < 4; ++r) {
                float e = __expf(fmaf(sc[hf][r], ATT_SCALE, -8.0f));
                if (!full) {
                    int q  = q0w + quad * 4 + r;
                    int dq = kkey - q;
                    bool valid = (kkey >= 0) && (kkey < S_LEN) && (dq <= WINSZ) && (dq >= -WINSZ);
                    e = valid ? e : 0.f;
                }
                p[hf][r] = e;
                lsum[r] += e;
            }
        }

        // P (C-layout) -> wave-private LDS -> A-layout frags
        unsigned short* pw = &Pls[wave][0];
#pragma unroll
        for (int hf = 0; hf < 4; ++hf)
#pragma unroll
            for (int r = 0; r < 4; ++r)
                pw[(quad * 4 + r) * 72 + hf * 16 + col] = f2bf_rhu(p[hf][r]);
        asm volatile("s_waitcnt lgkmcnt(0)" ::: "memory");
        bf16x8 pf[2];
        pf[0] = *(const bf16x8*)(&pw[col * 72 + quad * 8]);
        pf[1] = *(const bf16x8*)(&pw[col * 72 + 32 + quad * 8]);

        // O += P V : B-frags from transposed-V rows (swizzled chunks)
#pragma unroll
        for (int d = 0; d < 4; ++d) {
            const int rw = (d * 16 + col) * 64;
#pragma unroll
            for (int kc = 0; kc < 2; ++kc) {
                const int so = ((kc * 4 + swz) ^ (col & 7)) * 8;
                bf16x8 vf = *(const bf16x8*)(&Vls[rw + so]);
                acc[d] = __builtin_amdgcn_mfma_f32_16x16x32_bf16(pf[kc], vf, acc[d], 0, 0, 0);
            }
        }
    }

    // epilogue: final l-reduction, normalize, write ctx bf16 [b, s, h*64+d]
    const int b = bh >> 4, h = bh & 15;
#pragma unroll
    for (int r = 0; r < 4; ++r) {
        float v = lsum[r];
        v += __shfl_xor(v, 1);
        v += __shfl_xor(v, 2);
        v += __shfl_xor(v, 4);
        v += __shfl_xor(v, 8);
        float inv = 1.f / v;
        int q = q0w + quad * 4 + r;
#pragma unroll
        for (int d = 0; d < 4; ++d)
            ctx[((size_t)(b * S_LEN + q)) * 1024 + h * 64 + d * 16 + col] =
                f2bf(acc[d][r] * inv);
    }
}

// ---------------- launch ----------------
extern "C" void kernel_launch(void* const* d_in, const int* in_sizes, int n_in,
                              void* d_out, int out_size, void* d_ws, size_t ws_size,
                              hipStream_t stream) {
    const float* x    = (const float*)d_in[0];   // [2,2048,1024]
    const float* Wqkv = (const float*)d_in[1];   // [3072,1024]
    const float* Wout = (const float*)d_in[2];   // [1024,1024]
    const float* bout = (const float*)d_in[3];   // [1024]
    float* out = (float*)d_out;                  // [2,2048,1024] fp32

    char* ws = (char*)d_ws;
    unsigned short* xb    = (unsigned short*)(ws);                        // 4096x1024 bf16 (8 MB)
    unsigned short* wqkvb = (unsigned short*)(ws + 8u  * 1024 * 1024);    // 3072x1024 (6 MB)
    unsigned short* woutb = (unsigned short*)(ws + 14u * 1024 * 1024);    // 1024x1024 (2 MB)
    unsigned short* qb    = (unsigned short*)(ws + 16u * 1024 * 1024);    // [2,16,2048,64] (8 MB)
    unsigned short* kbuf  = (unsigned short*)(ws + 24u * 1024 * 1024);    // [2,16,2048,64] (8 MB)
    unsigned short* vtbuf = (unsigned short*)(ws + 32u * 1024 * 1024);    // [2,16,64,2048] (8 MB)
    unsigned short* ctxb  = (unsigned short*)(ws + 40u * 1024 * 1024);    // 4096x1024 (8 MB)

    cvt_all<<<8192, 256, 0, stream>>>(x, Wqkv, Wout, xb, wqkvb, woutb);

    // qkv = x @ Wqkv^T  -> q/k row-major, V transposed (C^T computed in-loop)
    gemm_bt<0, 128><<<dim3(24, 32), 256, 0, stream>>>(xb, wqkvb, 1024, qb, kbuf, vtbuf,
                                                      nullptr, nullptr, 0);
    // banded attention -> ctx  (16 q-tiles x 32 batch*heads, 512 threads)
    attn_kernel<<<dim3(16, 32), 512, 0, stream>>>(qb, kbuf, vtbuf, ctxb);
    // out = ctx @ Wout^T + b_out
    gemm_bt<1, 64><<<dim3(16, 32), 256, 0, stream>>>(ctxb, woutb, 1024, nullptr, nullptr, nullptr,
                                                     out, bout, 1024);
}

// Round 6
// 159.265 us; speedup vs baseline: 1.3791x; 1.3333x over previous
//
#include <hip/hip_runtime.h>

// Problem constants
#define S_LEN   2048
#define N_HEAD  16
#define WINSZ   256
#define ATT_SCALE 0.125f   // 1/sqrt(64)

typedef short bf16x8 __attribute__((ext_vector_type(8)));   // 8 bf16 (4 VGPRs) MFMA A/B frag
typedef float f32x4  __attribute__((ext_vector_type(4)));   // MFMA C/D frag

__device__ __forceinline__ unsigned short f2bf(float f) {   // RNE
    union { float f; unsigned u; } x; x.f = f;
    return (unsigned short)((x.u + 0x7FFFu + ((x.u >> 16) & 1u)) >> 16);
}
__device__ __forceinline__ unsigned short f2bf_rhu(float f) {  // round-half-up (cheap)
    union { float f; unsigned u; } x; x.f = f;
    return (unsigned short)((x.u + 0x8000u) >> 16);
}

// async global -> LDS, 16 B per lane (global_load_lds_dwordx4). LDS dest is
// wave-uniform base + lane*16 (m104/m108); global address may be per-lane.
__device__ __forceinline__ void gl2lds16(const unsigned short* g, unsigned short* l) {
    __builtin_amdgcn_global_load_lds(
        (const __attribute__((address_space(1))) unsigned int*)g,
        (__attribute__((address_space(3))) unsigned int*)l, 16, 0, 0);
}

// ---------------- fused fp32 -> bf16 conversion (all three tensors) ----------------
__global__ void cvt_all(const float* __restrict__ x, const float* __restrict__ wqkv,
                        const float* __restrict__ wout,
                        unsigned short* __restrict__ xb, unsigned short* __restrict__ wqkvb,
                        unsigned short* __restrict__ woutb) {
    int i = blockIdx.x * 256 + threadIdx.x;   // float4 units; total 2097152
    const float4* src; ushort4* dst; int off;
    if (i < 1048576)              { src = (const float4*)x;    dst = (ushort4*)xb;    off = i; }
    else if (i < 1048576 + 786432){ src = (const float4*)wqkv; dst = (ushort4*)wqkvb; off = i - 1048576; }
    else                          { src = (const float4*)wout; dst = (ushort4*)woutb; off = i - 1835008; }
    float4 v = src[off];
    ushort4 o;
    o.x = f2bf(v.x); o.y = f2bf(v.y); o.z = f2bf(v.z); o.w = f2bf(v.w);
    dst[off] = o;
}

// ---------------- bf16 GEMM: C[M,N] = A[M,K] * B[N,K]^T ----------------
// r3-measured-good structure: BK=64, global_load_lds width-16 staging with
// XOR-swizzled 16B chunks (conflict-free ds_read_b128), branch-free K-loop,
// DIRECT scatter epilogue (per-lane stores; same-block L2 merge keeps HBM
// write traffic at payload size — measured WRITE 24.6 MB in r2).
// MODE 0 (BN=128): scatter qkv: q,k -> [b,h,s,64]; V -> transposed [b,h,64,s]
// MODE 1 (BN=64) : fp32 C + bias
template<int MODE, int BN>
__global__ __launch_bounds__(256, 3)
void gemm_bt(const unsigned short* __restrict__ A, const unsigned short* __restrict__ Bm,
             int K,
             unsigned short* __restrict__ qout, unsigned short* __restrict__ kout,
             unsigned short* __restrict__ vtout,
             float* __restrict__ Cout, const float* __restrict__ bias, int N)
{
    constexpr int NJ = BN / 32;                 // n-frags per wave (4 or 2)
    __shared__ unsigned short Als[128 * 64];    // 16 KB
    __shared__ unsigned short Bls[BN * 64];     // 16 or 8 KB

    const int tid   = threadIdx.x;
    const int lane  = tid & 63;
    const int wave  = tid >> 6;
    const int bm    = blockIdx.y, bn = blockIdx.x;
    const int wm    = (wave >> 1) * 64;
    const int wn    = (wave & 1) * (BN / 2);
    const int col16 = lane & 15;
    const int quad  = lane >> 4;

    f32x4 acc[4][NJ];
#pragma unroll
    for (int i = 0; i < 4; ++i)
#pragma unroll
        for (int j = 0; j < NJ; ++j)
            acc[i][j] = f32x4{0.f, 0.f, 0.f, 0.f};

    // staging: each gl2lds16 fills 8 rows x 64ch. lane l -> row (l>>3),
    // GLOBAL 16B-chunk ((l&7)^(l>>3)) stored at PHYS chunk (l&7):
    // phys chunk p of LDS row r holds logical chunk p ^ (r&7).
    const int    grow     = lane >> 3;
    const int    gchk     = (lane & 7) ^ grow;
    const size_t laneoff  = (size_t)grow * K + gchk * 8;
    const unsigned short* gA = A  + (size_t)(bm * 128) * K + laneoff;
    const unsigned short* gB = Bm + (size_t)(bn * BN)  * K + laneoff;

    for (int k0 = 0; k0 < K; k0 += 64) {
        __syncthreads();
#pragma unroll
        for (int i = 0; i < 4; ++i) {
            const int r0 = wave * 32 + i * 8;
            gl2lds16(gA + (size_t)r0 * K + k0, &Als[r0 * 64]);
        }
#pragma unroll
        for (int i = 0; i < BN / 32; ++i) {
            const int r0 = wave * (BN / 4) + i * 8;
            gl2lds16(gB + (size_t)r0 * K + k0, &Bls[r0 * 64]);
        }
        __syncthreads();

#pragma unroll
        for (int kc = 0; kc < 2; ++kc) {
            bf16x8 af[4], bfr[NJ];
            const int sw = (kc * 4 + quad) ^ (col16 & 7);   // de-swizzle
#pragma unroll
            for (int i = 0; i < 4; ++i)
                af[i]  = *(const bf16x8*)(&Als[(wm + i * 16 + col16) * 64 + sw * 8]);
#pragma unroll
            for (int j = 0; j < NJ; ++j)
                bfr[j] = *(const bf16x8*)(&Bls[(wn + j * 16 + col16) * 64 + sw * 8]);
#pragma unroll
            for (int i = 0; i < 4; ++i)
#pragma unroll
                for (int j = 0; j < NJ; ++j)
                    acc[i][j] = __builtin_amdgcn_mfma_f32_16x16x32_bf16(af[i], bfr[j], acc[i][j], 0, 0, 0);
        }
    }

    // epilogue: C row = quad*4+reg, col = lane&15 (m89 layout)
    if (MODE == 0) {
        const int which = bn >> 3;   // block-uniform: 0=q, 1=k, 2=v
#pragma unroll
        for (int i = 0; i < 4; ++i)
#pragma unroll
            for (int j = 0; j < NJ; ++j)
#pragma unroll
                for (int r = 0; r < 4; ++r) {
                    int m = bm * 128 + wm + i * 16 + quad * 4 + r;
                    int n = bn * BN  + wn + j * 16 + col16;
                    int rem = n & 1023;
                    int h = rem >> 6, d = rem & 63;
                    int b = m >> 11, s = m & 2047;
                    unsigned short bv = f2bf(acc[i][j][r]);
                    if (which == 0)
                        qout[((size_t)(b * N_HEAD + h) * S_LEN + s) * 64 + d] = bv;
                    else if (which == 1)
                        kout[((size_t)(b * N_HEAD + h) * S_LEN + s) * 64 + d] = bv;
                    else
                        vtout[((size_t)(b * N_HEAD + h) * 64 + d) * S_LEN + s] = bv;
                }
    } else {
#pragma unroll
        for (int i = 0; i < 4; ++i)
#pragma unroll
            for (int j = 0; j < NJ; ++j)
#pragma unroll
                for (int r = 0; r < 4; ++r) {
                    int m = bm * 128 + wm + i * 16 + quad * 4 + r;
                    int n = bn * BN  + wn + j * 16 + col16;
                    Cout[(size_t)m * N + n] = acc[i][j][r] + bias[n];
                }
    }
}

// ---------------- banded flash attention ----------------
// 128-query blocks, 8 waves x 16 queries (512 threads). 64-key chunks staged
// via global_load_lds with XOR-chunk swizzle. Fixed-max softmax:
// p = exp(s*scale - 8) (scores bounded); exp(-8) cancels in O = PV/l.
__global__ __launch_bounds__(512, 4)
void attn_kernel(const unsigned short* __restrict__ Qg, const unsigned short* __restrict__ Kg,
                 const unsigned short* __restrict__ Vtg, unsigned short* __restrict__ ctx)
{
    __shared__ unsigned short Kls[64 * 64];        // 8 KB   [key][ch], swizzled chunks
    __shared__ unsigned short Vls[64 * 64];        // 8 KB   [d][key],  swizzled chunks
    __shared__ unsigned short Pls[8][16 * 72];     // 18 KB  per-wave P (LP=72)

    const int tid  = threadIdx.x;
    const int lane = tid & 63;
    const int wave = tid >> 6;            // 0..7
    const int col  = lane & 15;
    const int quad = lane >> 4;

    const int bh  = blockIdx.y;           // b*16 + h
    const int Q0  = blockIdx.x * 128;
    const int q0w = Q0 + wave * 16;

    const unsigned short* Qb  = Qg  + (size_t)bh * S_LEN * 64;
    const unsigned short* Kb  = Kg  + (size_t)bh * S_LEN * 64;
    const unsigned short* Vtb = Vtg + (size_t)bh * 64 * S_LEN;

    // Q fragment (A-operand m=lane&15, k=quad*8+j), two 32-channel chunks
    bf16x8 qa[2];
#pragma unroll
    for (int kc = 0; kc < 2; ++kc)
        qa[kc] = *(const bf16x8*)(Qb + (size_t)(q0w + col) * 64 + kc * 32 + quad * 8);

    f32x4 acc[4];
    float lsum[4];
#pragma unroll
    for (int d = 0; d < 4; ++d) acc[d] = f32x4{0.f, 0.f, 0.f, 0.f};
#pragma unroll
    for (int r = 0; r < 4; ++r) lsum[r] = 0.f;

    // staging lane roles (per wave: one 8-row K call + one 8-row V call)
    const int rsub = lane >> 3;                 // 0..7
    const int gch  = (lane & 7) ^ rsub;         // swizzled logical chunk
    const int swz  = quad;

    for (int c = 0; c < 10; ++c) {           // 10*64 = 640 keys covers [Q0-256, Q0+383]
        const int kb = Q0 - WINSZ + c * 64;
        __syncthreads();                     // previous-iter readers done
        {
            int krow = kb + wave * 8 + rsub;
            krow = krow < 0 ? 0 : (krow > S_LEN - 1 ? S_LEN - 1 : krow);
            gl2lds16(Kb + (size_t)krow * 64 + gch * 8, &Kls[wave * 512]);
            int drow = wave * 8 + rsub;
            int ss = kb + gch * 8;           // 8-granular; OOB keys masked below
            ss = ss < 0 ? 0 : (ss > S_LEN - 8 ? S_LEN - 8 : ss);
            gl2lds16(Vtb + (size_t)drow * S_LEN + ss, &Vls[wave * 512]);
        }
        __syncthreads();                     // drains vmcnt before barrier

        // wave-uniform skip of fully-masked chunks (both barriers already done)
        if (kb > q0w + 15 + WINSZ || kb + 63 < q0w - WINSZ || kb > S_LEN - 1 || kb + 63 < 0)
            continue;

        // S = Q K^T : 4 key-groups of 16
        f32x4 sc[4];
#pragma unroll
        for (int hf = 0; hf < 4; ++hf) {
            const int rw = (hf * 16 + col) * 64;
            const int s0 = ((0 * 4 + swz) ^ (col & 7)) * 8;
            const int s1 = ((1 * 4 + swz) ^ (col & 7)) * 8;
            bf16x8 kf0 = *(const bf16x8*)(&Kls[rw + s0]);
            bf16x8 kf1 = *(const bf16x8*)(&Kls[rw + s1]);
            f32x4 z = f32x4{0.f, 0.f, 0.f, 0.f};
            z = __builtin_amdgcn_mfma_f32_16x16x32_bf16(qa[0], kf0, z, 0, 0, 0);
            sc[hf] = __builtin_amdgcn_mfma_f32_16x16x32_bf16(qa[1], kf1, z, 0, 0, 0);
        }

        const bool full = (kb >= q0w + 15 - WINSZ) && (kb + 63 <= q0w + WINSZ) &&
                          (kb >= 0) && (kb + 63 <= S_LEN - 1);

        // p = exp(s*scale - 8); mask only boundary chunks
        float p[4][4];
#pragma unroll
        for (int hf = 0; hf < 4; ++hf) {
            const int kkey = kb + hf * 16 + col;
#pragma unroll
            for (int r = 0; r < 4; ++r) {
                float e = __expf(fmaf(sc[hf][r], ATT_SCALE, -8.0f));
                if (!full) {
                    int q  = q0w + quad * 4 + r;
                    int dq = kkey - q;
                    bool valid = (kkey >= 0) && (kkey < S_LEN) && (dq <= WINSZ) && (dq >= -WINSZ);
                    e = valid ? e : 0.f;
                }
                p[hf][r] = e;
                lsum[r] += e;
            }
        }

        // P (C-layout) -> wave-private LDS -> A-layout frags
        unsigned short* pw = &Pls[wave][0];
#pragma unroll
        for (int hf = 0; hf < 4; ++hf)
#pragma unroll
            for (int r = 0; r < 4; ++r)
                pw[(quad * 4 + r) * 72 + hf * 16 + col] = f2bf_rhu(p[hf][r]);
        asm volatile("s_waitcnt lgkmcnt(0)" ::: "memory");
        bf16x8 pf[2];
        pf[0] = *(const bf16x8*)(&pw[col * 72 + quad * 8]);
        pf[1] = *(const bf16x8*)(&pw[col * 72 + 32 + quad * 8]);

        // O += P V : B-frags from transposed-V rows (swizzled chunks)
#pragma unroll
        for (int d = 0; d < 4; ++d) {
            const int rw = (d * 16 + col) * 64;
#pragma unroll
            for (int kc = 0; kc < 2; ++kc) {
                const int so = ((kc * 4 + swz) ^ (col & 7)) * 8;
                bf16x8 vf = *(const bf16x8*)(&Vls[rw + so]);
                acc[d] = __builtin_amdgcn_mfma_f32_16x16x32_bf16(pf[kc], vf, acc[d], 0, 0, 0);
            }
        }
    }

    // epilogue: final l-reduction, normalize, write ctx bf16 [b, s, h*64+d]
    const int b = bh >> 4, h = bh & 15;
#pragma unroll
    for (int r = 0; r < 4; ++r) {
        float v = lsum[r];
        v += __shfl_xor(v, 1);
        v += __shfl_xor(v, 2);
        v += __shfl_xor(v, 4);
        v += __shfl_xor(v, 8);
        float inv = 1.f / v;
        int q = q0w + quad * 4 + r;
#pragma unroll
        for (int d = 0; d < 4; ++d)
            ctx[((size_t)(b * S_LEN + q)) * 1024 + h * 64 + d * 16 + col] =
                f2bf(acc[d][r] * inv);
    }
}

// ---------------- launch ----------------
extern "C" void kernel_launch(void* const* d_in, const int* in_sizes, int n_in,
                              void* d_out, int out_size, void* d_ws, size_t ws_size,
                              hipStream_t stream) {
    const float* x    = (const float*)d_in[0];   // [2,2048,1024]
    const float* Wqkv = (const float*)d_in[1];   // [3072,1024]
    const float* Wout = (const float*)d_in[2];   // [1024,1024]
    const float* bout = (const float*)d_in[3];   // [1024]
    float* out = (float*)d_out;                  // [2,2048,1024] fp32

    char* ws = (char*)d_ws;
    unsigned short* xb    = (unsigned short*)(ws);                        // 4096x1024 bf16 (8 MB)
    unsigned short* wqkvb = (unsigned short*)(ws + 8u  * 1024 * 1024);    // 3072x1024 (6 MB)
    unsigned short* woutb = (unsigned short*)(ws + 14u * 1024 * 1024);    // 1024x1024 (2 MB)
    unsigned short* qb    = (unsigned short*)(ws + 16u * 1024 * 1024);    // [2,16,2048,64] (8 MB)
    unsigned short* kbuf  = (unsigned short*)(ws + 24u * 1024 * 1024);    // [2,16,2048,64] (8 MB)
    unsigned short* vtbuf = (unsigned short*)(ws + 32u * 1024 * 1024);    // [2,16,64,2048] (8 MB)
    unsigned short* ctxb  = (unsigned short*)(ws + 40u * 1024 * 1024);    // 4096x1024 (8 MB)

    cvt_all<<<8192, 256, 0, stream>>>(x, Wqkv, Wout, xb, wqkvb, woutb);

    // qkv = x @ Wqkv^T  -> q/k row-major, V transposed (scatter epilogue)
    gemm_bt<0, 128><<<dim3(24, 32), 256, 0, stream>>>(xb, wqkvb, 1024, qb, kbuf, vtbuf,
                                                      nullptr, nullptr, 0);
    // banded attention -> ctx  (16 q-tiles x 32 batch*heads, 512 threads)
    attn_kernel<<<dim3(16, 32), 512, 0, stream>>>(qb, kbuf, vtbuf, ctxb);
    // out = ctx @ Wout^T + b_out
    gemm_bt<1, 64><<<dim3(16, 32), 256, 0, stream>>>(ctxb, woutb, 1024, nullptr, nullptr, nullptr,
                                                     out, bout, 1024);
}